// Round 7
// baseline (330.368 us; speedup 1.0000x reference)
//
#include <hip/hip_runtime.h>
#include <hip/hip_fp16.h>
#include <math.h>

#define IN_CH 128
#define HEADS 8
#define HID 16
#define OUT_CH 16
#define NEG 0.2f
#define NPB 256          // nodes per bucket (>>8)
#define MAXBUCK 400
#define AST 136          // LDS k-stride in halfs (128 + 8 pad)

__device__ __forceinline__ float lrelu(float x){ return x > 0.f ? x : NEG * x; }
__device__ __forceinline__ float elu_fast(float x){ return x > 0.f ? x : __expf(x) - 1.f; }

typedef _Float16 half8 __attribute__((ext_vector_type(8)));
typedef float    f32x4 __attribute__((ext_vector_type(4)));

// ---------------- bucketed CSR build ----------------
__global__ __launch_bounds__(256) void k_bhist(const int* __restrict__ tgt, int E, int nbuck, int epb,
                                               int* __restrict__ bcnt){
    __shared__ int hist[MAXBUCK];
    int tid = threadIdx.x;
    for (int i = tid; i < nbuck; i += 256) hist[i] = 0;
    __syncthreads();
    int start = blockIdx.x * epb, end = min(start + epb, E);
    for (int e = start + tid; e < end; e += 256) atomicAdd(&hist[tgt[e] >> 8], 1);
    __syncthreads();
    for (int i = tid; i < nbuck; i += 256) if (hist[i]) atomicAdd(&bcnt[i], hist[i]);
}

__global__ void k_bscan(const int* __restrict__ bcnt, int nbuck, int E,
                        int* __restrict__ boffs, int* __restrict__ bcur){
    __shared__ int s[512];
    int t = threadIdx.x;
    int v = (t < nbuck) ? bcnt[t] : 0;
    int orig = v;
    s[t] = v; __syncthreads();
    for (int off = 1; off < 512; off <<= 1){
        int u = (t >= off) ? s[t - off] : 0;
        __syncthreads();
        v += u; s[t] = v; __syncthreads();
    }
    if (t < nbuck){ boffs[t] = v - orig; bcur[t] = v - orig; }
    if (t == 0) boffs[nbuck] = E;
}

__global__ __launch_bounds__(256) void k_bscatter(const int* __restrict__ ei, int E, int nbuck, int epb,
                                                  int* __restrict__ bcur, int2* __restrict__ ebuck){
    __shared__ int hist[MAXBUCK];
    __shared__ int base[MAXBUCK];
    int tid = threadIdx.x;
    for (int i = tid; i < nbuck; i += 256) hist[i] = 0;
    __syncthreads();
    int start = blockIdx.x * epb, end = min(start + epb, E);
    for (int e = start + tid; e < end; e += 256) atomicAdd(&hist[ei[E + e] >> 8], 1);
    __syncthreads();
    for (int i = tid; i < nbuck; i += 256){
        base[i] = hist[i] ? atomicAdd(&bcur[i], hist[i]) : 0;
        hist[i] = 0;
    }
    __syncthreads();
    for (int e = start + tid; e < end; e += 256){
        int s = ei[e], t = ei[E + e];
        int b = t >> 8;
        int r = atomicAdd(&hist[b], 1);
        ebuck[base[b] + r] = make_int2(s, t);
    }
}

__global__ __launch_bounds__(256) void k_csr(const int2* __restrict__ ebuck, const int* __restrict__ boffs,
                                             int N, int E,
                                             int* __restrict__ offs, int* __restrict__ esrc){
    __shared__ int cnt[256];
    __shared__ int sscan[256];
    __shared__ int wcur[256];
    int b = blockIdx.x;
    int tid = threadIdx.x;
    int n0 = b * 256;
    int nn = min(256, N - n0);
    cnt[tid] = (tid < nn) ? 1 : 0;
    __syncthreads();
    int e0 = boffs[b], e1 = boffs[b + 1];
    for (int e = e0 + tid; e < e1; e += 256) atomicAdd(&cnt[ebuck[e].y & 255], 1);
    __syncthreads();
    int v = cnt[tid], orig = v;
    sscan[tid] = v; __syncthreads();
    for (int off = 1; off < 256; off <<= 1){
        int u = (tid >= off) ? sscan[tid - off] : 0;
        __syncthreads();
        v += u; sscan[tid] = v; __syncthreads();
    }
    int excl = v - orig;
    int gbase = e0 + n0;
    if (tid < nn){
        offs[n0 + tid] = gbase + excl;
        esrc[gbase + excl] = n0 + tid;
    }
    wcur[tid] = excl + 1;
    __syncthreads();
    for (int e = e0 + tid; e < e1; e += 256){
        int2 p = ebuck[e];
        int r = atomicAdd(&wcur[p.y & 255], 1);
        esrc[gbase + r] = p.x;
    }
    if (b == 0 && tid == 0) offs[N] = E + N;
}

// ---------------- GEMM1 (MFMA fp16): h1 = x @ W1 -> fp16 [N][128] ----------------
__global__ __launch_bounds__(256) void k_gemm1(const float* __restrict__ x, const float* __restrict__ W1,
                                               __half* __restrict__ h1, int N){
    __shared__ _Float16 sA[64*AST];    // 17.4 KB
    __shared__ _Float16 sB[128*AST];   // 34.8 KB
    int tid = threadIdx.x;
    for (int i = tid; i < 128*32; i += 256){
        int k = i >> 5, c0 = (i & 31) * 4;
        float4 w4 = *(const float4*)(W1 + k*128 + c0);
        sB[(c0+0)*AST + k] = (_Float16)w4.x;
        sB[(c0+1)*AST + k] = (_Float16)w4.y;
        sB[(c0+2)*AST + k] = (_Float16)w4.z;
        sB[(c0+3)*AST + k] = (_Float16)w4.w;
    }
    int row0 = blockIdx.x * 64;
    #pragma unroll
    for (int i = 0; i < 8; ++i){
        int q = i*256 + tid;
        int r = q >> 5, seg = q & 31;
        float4 v = make_float4(0.f,0.f,0.f,0.f);
        if (row0 + r < N) v = *(const float4*)(x + (size_t)(row0+r)*128 + seg*4);
        _Float16* dst = &sA[r*AST + seg*4];
        dst[0]=(_Float16)v.x; dst[1]=(_Float16)v.y; dst[2]=(_Float16)v.z; dst[3]=(_Float16)v.w;
    }
    __syncthreads();
    int wave = tid >> 6, lane = tid & 63;
    int m = lane & 15, quad = lane >> 4;
    int rbase = wave * 16;
    f32x4 acc[8] = {};
    #pragma unroll
    for (int kc = 0; kc < 4; ++kc){
        int kb = kc*32 + quad*8;
        half8 a = *(half8*)(&sA[(rbase + m)*AST + kb]);
        #pragma unroll
        for (int t = 0; t < 8; ++t){
            half8 b = *(half8*)(&sB[(t*16 + m)*AST + kb]);
            acc[t] = __builtin_amdgcn_mfma_f32_16x16x32_f16(a, b, acc[t], 0, 0, 0);
        }
    }
    #pragma unroll
    for (int t = 0; t < 8; ++t){
        #pragma unroll
        for (int j = 0; j < 4; ++j){
            int r = row0 + rbase + quad*4 + j;
            if (r < N) h1[(size_t)r*128 + t*16 + m] = __float2half(acc[t][j]);
        }
    }
}

// ---------------- attention logits + per-(node,head) int8 quantization ----------------
struct H8 { __half2 v[8]; };

__global__ void k_alpha1(const __half2* __restrict__ h1h, const float* __restrict__ asrc, const float* __restrict__ adst,
                         float2* __restrict__ asw, float* __restrict__ ad1,
                         unsigned char* __restrict__ h1q, int N){
    int idx = blockIdx.x*blockDim.x + threadIdx.x;
    if (idx >= N*HEADS) return;
    int h = idx & 7;
    int n = idx >> 3;
    H8 blk = *(const H8*)(h1h + (size_t)n*64 + h*8);
    const float2* sp = (const float2*)(asrc + h*16);
    const float2* dp = (const float2*)(adst + h*16);
    float fv[16];
    float ss = 0.f, dd = 0.f;
    #pragma unroll
    for (int j = 0; j < 8; ++j){
        float2 v = __half22float2(blk.v[j]);
        fv[2*j] = v.x; fv[2*j+1] = v.y;
        float2 a = sp[j], b = dp[j];
        ss += v.x*a.x + v.y*a.y;
        dd += v.x*b.x + v.y*b.y;
    }
    float mx = 1e-12f;
    #pragma unroll
    for (int k = 0; k < 16; ++k) mx = fmaxf(mx, fabsf(fv[k]));
    float rs = 127.f / mx;
    unsigned int w[4];
    #pragma unroll
    for (int d = 0; d < 4; ++d){
        unsigned int b0 = (unsigned int)((int)rintf(fv[4*d+0]*rs) + 128);
        unsigned int b1 = (unsigned int)((int)rintf(fv[4*d+1]*rs) + 128);
        unsigned int b2 = (unsigned int)((int)rintf(fv[4*d+2]*rs) + 128);
        unsigned int b3 = (unsigned int)((int)rintf(fv[4*d+3]*rs) + 128);
        w[d] = b0 | (b1 << 8) | (b2 << 16) | (b3 << 24);
    }
    asw[idx] = make_float2(ss, mx * (1.f/127.f));
    ad1[idx] = dd;
    *(uint4*)(h1q + (size_t)idx*16) = make_uint4(w[0], w[1], w[2], w[3]);
}

// ---------------- layer-1 aggregation: int8 gather, 2 nodes/wave, 8 lanes/edge, 16 ch/lane ----
// nsub = l>>5 picks the node; slot = (l>>3)&3 is the edge slot; c = l&7 is the head
// (channels 16c..16c+15 = one dwordx4 of the int8 row = one 128B L2 line per edge).
// Per-edge: w = exp(lrelu(as+ad)); wq = w*scale folded so decode is cvt_ubyte+fma;
// bias correction -128*sum(wq) applied after the cross-slot reduce.
// Epilogue is spread over all 4 slots (slot s finishes channels 4s..4s+3) with
// static-index selects (no runtime array indexing -> no scratch). ELU = expf-1.
__global__ __launch_bounds__(256) void k_agg1(const unsigned char* __restrict__ h1q, const float2* __restrict__ asw,
                                              const float* __restrict__ ad1,
                                              const int* __restrict__ offs, const int* __restrict__ esrc,
                                              const float* __restrict__ b1, __half2* __restrict__ hl2h,
                                              int nbase, int nend){
    int wv = threadIdx.x >> 6;
    int l  = threadIdx.x & 63;
    int nsub = l >> 5;
    int slot = (l >> 3) & 3;
    int c    = l & 7;
    int n = nbase + blockIdx.x*8 + wv*2 + nsub;
    bool alive = (n < nend);
    float adc = 0.f;
    int e0 = 0, deg = 0;
    if (alive){
        adc = ad1[n*8 + c];
        e0 = offs[n];
        deg = offs[n+1] - e0;
    }
    int degmax = max(deg, __shfl_xor(deg, 32));

    float acc[16] = {};
    float den = 0.f;     // sum of w
    float dq  = 0.f;     // sum of w*scale
    for (int i = 0; i < degmax; i += 8){
        int j0 = i + slot, j1 = i + 4 + slot;
        bool v0 = j0 < deg, v1 = j1 < deg;
        int iA = e0 + (v0 ? j0 : 0);
        int iB = e0 + (v1 ? j1 : 0);
        int s0 = esrc[iA], s1 = esrc[iB];
        float2 aw0 = asw[s0*8 + c];
        float2 aw1 = asw[s1*8 + c];
        uint4 q0 = *(const uint4*)(h1q + (size_t)s0*128 + c*16);
        uint4 q1 = *(const uint4*)(h1q + (size_t)s1*128 + c*16);
        float w0 = v0 ? __expf(lrelu(aw0.x + adc)) : 0.f;
        float w1 = v1 ? __expf(lrelu(aw1.x + adc)) : 0.f;
        float wq0 = w0 * aw0.y;
        float wq1 = w1 * aw1.y;
        den += w0 + w1;
        dq  += wq0 + wq1;
        const unsigned int* u0 = (const unsigned int*)&q0;
        const unsigned int* u1 = (const unsigned int*)&q1;
        #pragma unroll
        for (int d = 0; d < 4; ++d){
            unsigned int a = u0[d], b = u1[d];
            acc[4*d+0] += wq0 * (float)(a & 255u);
            acc[4*d+1] += wq0 * (float)((a >> 8) & 255u);
            acc[4*d+2] += wq0 * (float)((a >> 16) & 255u);
            acc[4*d+3] += wq0 * (float)(a >> 24);
            acc[4*d+0] += wq1 * (float)(b & 255u);
            acc[4*d+1] += wq1 * (float)((b >> 8) & 255u);
            acc[4*d+2] += wq1 * (float)((b >> 16) & 255u);
            acc[4*d+3] += wq1 * (float)(b >> 24);
        }
    }
    // cross-slot reduce (within the 32-lane node group): every slot ends with full sums
    den += __shfl_xor(den, 8);  den += __shfl_xor(den, 16);
    dq  += __shfl_xor(dq, 8);   dq  += __shfl_xor(dq, 16);
    #pragma unroll
    for (int k = 0; k < 16; ++k){
        acc[k] += __shfl_xor(acc[k], 8);
        acc[k] += __shfl_xor(acc[k], 16);
    }
    if (!alive) return;
    float rd = 1.f / (den + 1e-16f);
    float bias128 = 128.f * dq;
    // slot s takes channels 4s..4s+3 via static-index selects
    float sel0, sel1, sel2, sel3;
    {
        float a0 = (slot & 1) ? acc[4]  : acc[0];
        float b0 = (slot & 1) ? acc[12] : acc[8];
        sel0 = (slot & 2) ? b0 : a0;
        float a1 = (slot & 1) ? acc[5]  : acc[1];
        float b1v = (slot & 1) ? acc[13] : acc[9];
        sel1 = (slot & 2) ? b1v : a1;
        float a2 = (slot & 1) ? acc[6]  : acc[2];
        float b2v = (slot & 1) ? acc[14] : acc[10];
        sel2 = (slot & 2) ? b2v : a2;
        float a3 = (slot & 1) ? acc[7]  : acc[3];
        float b3v = (slot & 1) ? acc[15] : acc[11];
        sel3 = (slot & 2) ? b3v : a3;
    }
    float4 b4 = *(const float4*)(b1 + c*16 + slot*4);
    float v0 = elu_fast((sel0 - bias128)*rd + b4.x);
    float v1 = elu_fast((sel1 - bias128)*rd + b4.y);
    float v2 = elu_fast((sel2 - bias128)*rd + b4.z);
    float v3 = elu_fast((sel3 - bias128)*rd + b4.w);
    __half2 q0h = __floats2half2_rn(v0, v1);
    __half2 q1h = __floats2half2_rn(v2, v3);
    float2 ov;
    *(__half2*)&ov.x = q0h; *(__half2*)&ov.y = q1h;
    *(float2*)(hl2h + (size_t)n*64 + c*8 + slot*2) = ov;
}

// ---------------- GEMM2: h2 = hl2 @ W2 -> fp16 + fused alpha2 ----------------
#define FMA4(acc, a, b) { acc.x += (a)*(b).x; acc.y += (a)*(b).y; acc.z += (a)*(b).z; acc.w += (a)*(b).w; }

__global__ __launch_bounds__(256) void k_gemm2(const __half2* __restrict__ hl2h, const float* __restrict__ W2,
                                               const float* __restrict__ asrc2, const float* __restrict__ adst2,
                                               __half2* __restrict__ h2h, float* __restrict__ as2, float* __restrict__ ad2,
                                               int N){
    __shared__ float sX[64*132];
    __shared__ float sW2[128*16];
    int tid = threadIdx.x;
    for (int i = tid; i < 128*16; i += 256) sW2[i] = W2[i];
    int row0 = blockIdx.x * 64;
    #pragma unroll
    for (int i = 0; i < 4; ++i){
        int q = i*256 + tid;
        int r = q >> 4, seg = q & 15;
        float4 raw = make_float4(0.f,0.f,0.f,0.f);
        if (row0 + r < N) raw = ((const float4*)(hl2h + (size_t)(row0+r)*64))[seg];
        const __half2* hp = (const __half2*)&raw;
        float* dst = &sX[r*132 + seg*8];
        #pragma unroll
        for (int j = 0; j < 4; ++j){
            float2 f = __half22float2(hp[j]);
            dst[2*j] = f.x; dst[2*j+1] = f.y;
        }
    }
    __syncthreads();
    int nd = tid >> 2;
    int cq = tid & 3, c0 = cq*4;
    int n = row0 + nd;
    float4 acc = make_float4(0.f,0.f,0.f,0.f);
    #pragma unroll 4
    for (int k4 = 0; k4 < 32; ++k4){
        float4 a  = *(const float4*)(&sX[nd*132 + k4*4]);
        float4 w0 = *(const float4*)(&sW2[(k4*4+0)*16 + c0]);
        float4 w1 = *(const float4*)(&sW2[(k4*4+1)*16 + c0]);
        float4 w2 = *(const float4*)(&sW2[(k4*4+2)*16 + c0]);
        float4 w3 = *(const float4*)(&sW2[(k4*4+3)*16 + c0]);
        FMA4(acc, a.x, w0); FMA4(acc, a.y, w1); FMA4(acc, a.z, w2); FMA4(acc, a.w, w3);
    }
    float ps = acc.x*asrc2[c0] + acc.y*asrc2[c0+1] + acc.z*asrc2[c0+2] + acc.w*asrc2[c0+3];
    float pd = acc.x*adst2[c0] + acc.y*adst2[c0+1] + acc.z*adst2[c0+2] + acc.w*adst2[c0+3];
    ps += __shfl_xor(ps, 1); ps += __shfl_xor(ps, 2);
    pd += __shfl_xor(pd, 1); pd += __shfl_xor(pd, 2);
    if (n < N){
        __half2 p0 = __floats2half2_rn(acc.x, acc.y);
        __half2 p1 = __floats2half2_rn(acc.z, acc.w);
        float2 ov;
        *(__half2*)&ov.x = p0; *(__half2*)&ov.y = p1;
        *(float2*)(h2h + (size_t)n*8 + cq*2) = ov;
        if (cq == 0){ as2[n] = ps; ad2[n] = pd; }
    }
}

// ---------------- layer-2 fused aggregation (half2 gather, 8 edges in flight) -> out ----------------
__global__ __launch_bounds__(256) void k_agg2(const __half2* __restrict__ h2h, const float* __restrict__ as2v,
                                              const float* __restrict__ ad2v,
                                              const int* __restrict__ offs, const int* __restrict__ esrc,
                                              const float* __restrict__ b2, float* __restrict__ out, int N){
    int n = blockIdx.x*4 + (threadIdx.x >> 6);
    if (n >= N) return;
    int l = threadIdx.x & 63;
    int e0 = offs[n], e1 = offs[n+1];
    float ad = ad2v[n];
    int eo = l >> 3, c2 = l & 7;
    float ax = 0.f, ay = 0.f, den = 0.f;
    for (int e = e0 + eo; e < e1; e += 8){
        int s = esrc[e];
        float w = __expf(lrelu(as2v[s] + ad));
        den += w;
        float2 f = __half22float2(h2h[(size_t)s*8 + c2]);
        ax += w * f.x; ay += w * f.y;
    }
    ax += __shfl_xor(ax, 8);  ay += __shfl_xor(ay, 8);  den += __shfl_xor(den, 8);
    ax += __shfl_xor(ax, 16); ay += __shfl_xor(ay, 16); den += __shfl_xor(den, 16);
    ax += __shfl_xor(ax, 32); ay += __shfl_xor(ay, 32); den += __shfl_xor(den, 32);
    if (eo == 0){
        float rd = 1.f / (den + 1e-16f);
        float2 bb = *(const float2*)(b2 + c2*2);
        float2 o = make_float2(ax*rd + bb.x, ay*rd + bb.y);
        *(float2*)(out + (size_t)n*16 + c2*2) = o;
    }
}

extern "C" void kernel_launch(void* const* d_in, const int* in_sizes, int n_in,
                              void* d_out, int out_size, void* d_ws, size_t ws_size,
                              hipStream_t stream){
    const float* x     = (const float*)d_in[0];
    const int*   ei    = (const int*)  d_in[1];
    const float* W1    = (const float*)d_in[2];
    const float* asrc1 = (const float*)d_in[3];
    const float* adst1 = (const float*)d_in[4];
    const float* b1    = (const float*)d_in[5];
    const float* W2    = (const float*)d_in[6];
    const float* asrc2 = (const float*)d_in[7];
    const float* adst2 = (const float*)d_in[8];
    const float* b2    = (const float*)d_in[9];
    float* out = (float*)d_out;

    const int N = in_sizes[0] / IN_CH;   // 100000
    const int E = in_sizes[1] / 2;       // 1600000
    const int ETOT = E + N;
    const int NBUCK = (N + NPB - 1) / NPB;   // 391

    char* p = (char*)d_ws;
    auto alloc = [&](size_t bytes) -> char* {
        char* r = p; p += (bytes + 255) & ~(size_t)255; return r;
    };
    __half2* h1h  = (__half2*)alloc((size_t)N * 64 * 4);
    __half2* hl2h = (__half2*)alloc((size_t)N * 64 * 4);
    unsigned char* h1q = (unsigned char*)alloc((size_t)N * 128);
    float2* asw  = (float2*)alloc((size_t)N * 8 * 8);
    float* ad1   = (float*)alloc((size_t)N * 8 * 4);
    __half2* h2h = (__half2*)alloc((size_t)N * 8 * 4);
    float* as2   = (float*)alloc((size_t)N * 4);
    float* ad2   = (float*)alloc((size_t)N * 4);
    int*   bcnt  = (int*)  alloc((size_t)MAXBUCK * 4);
    int*   boffs = (int*)  alloc((size_t)(MAXBUCK + 1) * 4);
    int*   bcur  = (int*)  alloc((size_t)MAXBUCK * 4);
    int*   offs  = (int*)  alloc((size_t)(N + 1) * 4);
    int*   esrc  = (int*)  alloc((size_t)ETOT * 4);
    int2*  ebuck = (int2*)hl2h;   // aliases hl2h; k_csr done before k_agg1 writes it

    (void)hipMemsetAsync(bcnt, 0, (size_t)NBUCK * 4, stream);

    const int GPART = 512;
    const int epb = (E + GPART - 1) / GPART;

    k_bhist   <<<GPART, 256, 0, stream>>>(ei + E, E, NBUCK, epb, bcnt);
    k_bscan   <<<1,     512, 0, stream>>>(bcnt, NBUCK, E, boffs, bcur);
    k_bscatter<<<GPART, 256, 0, stream>>>(ei, E, NBUCK, epb, bcur, ebuck);
    k_csr     <<<NBUCK, 256, 0, stream>>>(ebuck, boffs, N, E, offs, esrc);

    k_gemm1  <<<(N + 63) / 64, 256, 0, stream>>>(x, W1, (__half*)h1h, N);
    k_alpha1 <<<(N * HEADS + 255) / 256, 256, 0, stream>>>(h1h, asrc1, adst1, asw, ad1, h1q, N);

    // split k_agg1 into two node-range halves (profile visibility + scheduling)
    const int NH = ((N / 2) + 7) & ~7;   // 50000 -> multiple of 8
    k_agg1 <<<(NH + 7) / 8, 256, 0, stream>>>(h1q, asw, ad1, offs, esrc, b1, hl2h, 0, NH);
    k_agg1 <<<((N - NH) + 7) / 8, 256, 0, stream>>>(h1q, asw, ad1, offs, esrc, b1, hl2h, NH, N);

    k_gemm2  <<<(N + 63) / 64, 256, 0, stream>>>(hl2h, W2, asrc2, adst2, h2h, as2, ad2, N);
    k_agg2   <<<(N + 3) / 4, 256, 0, stream>>>(h2h, as2, ad2, offs, esrc, b2, out, N);
}

// Round 8
// 308.342 us; speedup vs baseline: 1.0714x; 1.0714x over previous
//
#include <hip/hip_runtime.h>
#include <hip/hip_fp16.h>
#include <math.h>

#define IN_CH 128
#define HEADS 8
#define HID 16
#define OUT_CH 16
#define NEG 0.2f
#define NPB 256          // nodes per bucket (>>8)
#define MAXBUCK 400
#define AST 136          // LDS k-stride in halfs (128 + 8 pad)

__device__ __forceinline__ float lrelu(float x){ return x > 0.f ? x : NEG * x; }
__device__ __forceinline__ float elu_fast(float x){ return x > 0.f ? x : __expf(x) - 1.f; }

typedef _Float16 half8 __attribute__((ext_vector_type(8)));
typedef float    f32x4 __attribute__((ext_vector_type(4)));

// ---------------- bucketed CSR build ----------------
__global__ __launch_bounds__(256) void k_bhist(const int* __restrict__ tgt, int E, int nbuck, int epb,
                                               int* __restrict__ bcnt){
    __shared__ int hist[MAXBUCK];
    int tid = threadIdx.x;
    for (int i = tid; i < nbuck; i += 256) hist[i] = 0;
    __syncthreads();
    int start = blockIdx.x * epb, end = min(start + epb, E);
    for (int e = start + tid; e < end; e += 256) atomicAdd(&hist[tgt[e] >> 8], 1);
    __syncthreads();
    for (int i = tid; i < nbuck; i += 256) if (hist[i]) atomicAdd(&bcnt[i], hist[i]);
}

__global__ void k_bscan(const int* __restrict__ bcnt, int nbuck, int E,
                        int* __restrict__ boffs, int* __restrict__ bcur){
    __shared__ int s[512];
    int t = threadIdx.x;
    int v = (t < nbuck) ? bcnt[t] : 0;
    int orig = v;
    s[t] = v; __syncthreads();
    for (int off = 1; off < 512; off <<= 1){
        int u = (t >= off) ? s[t - off] : 0;
        __syncthreads();
        v += u; s[t] = v; __syncthreads();
    }
    if (t < nbuck){ boffs[t] = v - orig; bcur[t] = v - orig; }
    if (t == 0) boffs[nbuck] = E;
}

__global__ __launch_bounds__(256) void k_bscatter(const int* __restrict__ ei, int E, int nbuck, int epb,
                                                  int* __restrict__ bcur, int2* __restrict__ ebuck){
    __shared__ int hist[MAXBUCK];
    __shared__ int base[MAXBUCK];
    int tid = threadIdx.x;
    for (int i = tid; i < nbuck; i += 256) hist[i] = 0;
    __syncthreads();
    int start = blockIdx.x * epb, end = min(start + epb, E);
    for (int e = start + tid; e < end; e += 256) atomicAdd(&hist[ei[E + e] >> 8], 1);
    __syncthreads();
    for (int i = tid; i < nbuck; i += 256){
        base[i] = hist[i] ? atomicAdd(&bcur[i], hist[i]) : 0;
        hist[i] = 0;
    }
    __syncthreads();
    for (int e = start + tid; e < end; e += 256){
        int s = ei[e], t = ei[E + e];
        int b = t >> 8;
        int r = atomicAdd(&hist[b], 1);
        ebuck[base[b] + r] = make_int2(s, t);
    }
}

__global__ __launch_bounds__(256) void k_csr(const int2* __restrict__ ebuck, const int* __restrict__ boffs,
                                             int N, int E,
                                             int* __restrict__ offs, int* __restrict__ esrc){
    __shared__ int cnt[256];
    __shared__ int sscan[256];
    __shared__ int wcur[256];
    int b = blockIdx.x;
    int tid = threadIdx.x;
    int n0 = b * 256;
    int nn = min(256, N - n0);
    cnt[tid] = (tid < nn) ? 1 : 0;
    __syncthreads();
    int e0 = boffs[b], e1 = boffs[b + 1];
    for (int e = e0 + tid; e < e1; e += 256) atomicAdd(&cnt[ebuck[e].y & 255], 1);
    __syncthreads();
    int v = cnt[tid], orig = v;
    sscan[tid] = v; __syncthreads();
    for (int off = 1; off < 256; off <<= 1){
        int u = (tid >= off) ? sscan[tid - off] : 0;
        __syncthreads();
        v += u; sscan[tid] = v; __syncthreads();
    }
    int excl = v - orig;
    int gbase = e0 + n0;
    if (tid < nn){
        offs[n0 + tid] = gbase + excl;
        esrc[gbase + excl] = n0 + tid;
    }
    wcur[tid] = excl + 1;
    __syncthreads();
    for (int e = e0 + tid; e < e1; e += 256){
        int2 p = ebuck[e];
        int r = atomicAdd(&wcur[p.y & 255], 1);
        esrc[gbase + r] = p.x;
    }
    if (b == 0 && tid == 0) offs[N] = E + N;
}

// ---------------- GEMM1 (MFMA fp16, persistent W1): h1 = x @ W1 -> fp16 [N][128] ----------------
// Grid-stride over 64-row tiles. W1 staged into LDS ONCE per block (scalar pattern,
// low-conflict); per tile: {commit prefetched x to sA[b], barrier, prefetch next tile
// to regs (VMEM in flight under MFMA), MFMA, store}, single barrier per tile with
// double-buffered sA (barrier(t) post-dates every wave's MFMA(t-1) -> WAR-safe).
__global__ __launch_bounds__(256) void k_gemm1(const float* __restrict__ x, const float* __restrict__ W1,
                                               __half* __restrict__ h1, int N, int NT){
    __shared__ _Float16 sB[128*AST];      // 34.8 KB (persistent)
    __shared__ _Float16 sA[2][64*AST];    // 2 x 17.4 KB double buffer
    int tid = threadIdx.x;
    for (int i = tid; i < 128*128; i += 256){
        int k = i >> 7, c = i & 127;
        sB[c*AST + k] = (_Float16)W1[i];
    }
    int wave = tid >> 6, lane = tid & 63;
    int m = lane & 15, quad = lane >> 4;
    int rbase = wave * 16;

    float4 vr[8];
    int tile = blockIdx.x;
    #pragma unroll
    for (int i = 0; i < 8; ++i){
        int q = i*256 + tid;
        int r = q >> 5, seg = q & 31;
        int row = tile*64 + r;
        vr[i] = make_float4(0.f,0.f,0.f,0.f);
        if (tile < NT && row < N) vr[i] = *(const float4*)(x + (size_t)row*128 + seg*4);
    }
    int b = 0;
    for (; tile < NT; tile += gridDim.x){
        #pragma unroll
        for (int i = 0; i < 8; ++i){
            int q = i*256 + tid;
            int r = q >> 5, seg = q & 31;
            _Float16* dst = &sA[b][r*AST + seg*4];
            dst[0]=(_Float16)vr[i].x; dst[1]=(_Float16)vr[i].y;
            dst[2]=(_Float16)vr[i].z; dst[3]=(_Float16)vr[i].w;
        }
        __syncthreads();
        int tn = tile + gridDim.x;
        #pragma unroll
        for (int i = 0; i < 8; ++i){
            int q = i*256 + tid;
            int r = q >> 5, seg = q & 31;
            int row = tn*64 + r;
            vr[i] = make_float4(0.f,0.f,0.f,0.f);
            if (tn < NT && row < N) vr[i] = *(const float4*)(x + (size_t)row*128 + seg*4);
        }
        f32x4 acc[8] = {};
        #pragma unroll
        for (int kc = 0; kc < 4; ++kc){
            int kb = kc*32 + quad*8;
            half8 a = *(half8*)(&sA[b][(rbase + m)*AST + kb]);
            #pragma unroll
            for (int t = 0; t < 8; ++t){
                half8 bb = *(half8*)(&sB[(t*16 + m)*AST + kb]);
                acc[t] = __builtin_amdgcn_mfma_f32_16x16x32_f16(a, bb, acc[t], 0, 0, 0);
            }
        }
        int row0 = tile*64;
        #pragma unroll
        for (int t = 0; t < 8; ++t){
            #pragma unroll
            for (int j = 0; j < 4; ++j){
                int r = row0 + rbase + quad*4 + j;
                if (r < N) h1[(size_t)r*128 + t*16 + m] = __float2half(acc[t][j]);
            }
        }
        b ^= 1;
    }
}

// ---------------- attention logits + per-(node,head) int8 quantization ----------------
struct H8 { __half2 v[8]; };

__global__ void k_alpha1(const __half2* __restrict__ h1h, const float* __restrict__ asrc, const float* __restrict__ adst,
                         float2* __restrict__ asw, float* __restrict__ ad1,
                         unsigned char* __restrict__ h1q, int N){
    int idx = blockIdx.x*blockDim.x + threadIdx.x;
    if (idx >= N*HEADS) return;
    int h = idx & 7;
    int n = idx >> 3;
    H8 blk = *(const H8*)(h1h + (size_t)n*64 + h*8);
    const float2* sp = (const float2*)(asrc + h*16);
    const float2* dp = (const float2*)(adst + h*16);
    float fv[16];
    float ss = 0.f, dd = 0.f;
    #pragma unroll
    for (int j = 0; j < 8; ++j){
        float2 v = __half22float2(blk.v[j]);
        fv[2*j] = v.x; fv[2*j+1] = v.y;
        float2 a = sp[j], b = dp[j];
        ss += v.x*a.x + v.y*a.y;
        dd += v.x*b.x + v.y*b.y;
    }
    float mx = 1e-12f;
    #pragma unroll
    for (int k = 0; k < 16; ++k) mx = fmaxf(mx, fabsf(fv[k]));
    float rs = 127.f / mx;
    unsigned int w[4];
    #pragma unroll
    for (int d = 0; d < 4; ++d){
        unsigned int b0 = (unsigned int)((int)rintf(fv[4*d+0]*rs) + 128);
        unsigned int b1 = (unsigned int)((int)rintf(fv[4*d+1]*rs) + 128);
        unsigned int b2 = (unsigned int)((int)rintf(fv[4*d+2]*rs) + 128);
        unsigned int b3 = (unsigned int)((int)rintf(fv[4*d+3]*rs) + 128);
        w[d] = b0 | (b1 << 8) | (b2 << 16) | (b3 << 24);
    }
    asw[idx] = make_float2(ss, mx * (1.f/127.f));
    ad1[idx] = dd;
    *(uint4*)(h1q + (size_t)idx*16) = make_uint4(w[0], w[1], w[2], w[3]);
}

// ---------------- layer-1 aggregation: int8 gather, 2 nodes/wave, 8 lanes/edge, 16 ch/lane ----
__global__ __launch_bounds__(256) void k_agg1(const unsigned char* __restrict__ h1q, const float2* __restrict__ asw,
                                              const float* __restrict__ ad1,
                                              const int* __restrict__ offs, const int* __restrict__ esrc,
                                              const float* __restrict__ b1, __half2* __restrict__ hl2h,
                                              int nbase, int nend){
    int wv = threadIdx.x >> 6;
    int l  = threadIdx.x & 63;
    int nsub = l >> 5;
    int slot = (l >> 3) & 3;
    int c    = l & 7;
    int n = nbase + blockIdx.x*8 + wv*2 + nsub;
    bool alive = (n < nend);
    float adc = 0.f;
    int e0 = 0, deg = 0;
    if (alive){
        adc = ad1[n*8 + c];
        e0 = offs[n];
        deg = offs[n+1] - e0;
    }
    int degmax = max(deg, __shfl_xor(deg, 32));

    float acc[16] = {};
    float den = 0.f;     // sum of w
    float dq  = 0.f;     // sum of w*scale
    for (int i = 0; i < degmax; i += 8){
        int j0 = i + slot, j1 = i + 4 + slot;
        bool v0 = j0 < deg, v1 = j1 < deg;
        int iA = e0 + (v0 ? j0 : 0);
        int iB = e0 + (v1 ? j1 : 0);
        int s0 = esrc[iA], s1 = esrc[iB];
        float2 aw0 = asw[s0*8 + c];
        float2 aw1 = asw[s1*8 + c];
        uint4 q0 = *(const uint4*)(h1q + (size_t)s0*128 + c*16);
        uint4 q1 = *(const uint4*)(h1q + (size_t)s1*128 + c*16);
        float w0 = v0 ? __expf(lrelu(aw0.x + adc)) : 0.f;
        float w1 = v1 ? __expf(lrelu(aw1.x + adc)) : 0.f;
        float wq0 = w0 * aw0.y;
        float wq1 = w1 * aw1.y;
        den += w0 + w1;
        dq  += wq0 + wq1;
        const unsigned int* u0 = (const unsigned int*)&q0;
        const unsigned int* u1 = (const unsigned int*)&q1;
        #pragma unroll
        for (int d = 0; d < 4; ++d){
            unsigned int a = u0[d], b = u1[d];
            acc[4*d+0] += wq0 * (float)(a & 255u);
            acc[4*d+1] += wq0 * (float)((a >> 8) & 255u);
            acc[4*d+2] += wq0 * (float)((a >> 16) & 255u);
            acc[4*d+3] += wq0 * (float)(a >> 24);
            acc[4*d+0] += wq1 * (float)(b & 255u);
            acc[4*d+1] += wq1 * (float)((b >> 8) & 255u);
            acc[4*d+2] += wq1 * (float)((b >> 16) & 255u);
            acc[4*d+3] += wq1 * (float)(b >> 24);
        }
    }
    den += __shfl_xor(den, 8);  den += __shfl_xor(den, 16);
    dq  += __shfl_xor(dq, 8);   dq  += __shfl_xor(dq, 16);
    #pragma unroll
    for (int k = 0; k < 16; ++k){
        acc[k] += __shfl_xor(acc[k], 8);
        acc[k] += __shfl_xor(acc[k], 16);
    }
    if (!alive) return;
    float rd = 1.f / (den + 1e-16f);
    float bias128 = 128.f * dq;
    float sel0, sel1, sel2, sel3;
    {
        float a0 = (slot & 1) ? acc[4]  : acc[0];
        float b0 = (slot & 1) ? acc[12] : acc[8];
        sel0 = (slot & 2) ? b0 : a0;
        float a1 = (slot & 1) ? acc[5]  : acc[1];
        float b1v = (slot & 1) ? acc[13] : acc[9];
        sel1 = (slot & 2) ? b1v : a1;
        float a2 = (slot & 1) ? acc[6]  : acc[2];
        float b2v = (slot & 1) ? acc[14] : acc[10];
        sel2 = (slot & 2) ? b2v : a2;
        float a3 = (slot & 1) ? acc[7]  : acc[3];
        float b3v = (slot & 1) ? acc[15] : acc[11];
        sel3 = (slot & 2) ? b3v : a3;
    }
    float4 b4 = *(const float4*)(b1 + c*16 + slot*4);
    float v0 = elu_fast((sel0 - bias128)*rd + b4.x);
    float v1 = elu_fast((sel1 - bias128)*rd + b4.y);
    float v2 = elu_fast((sel2 - bias128)*rd + b4.z);
    float v3 = elu_fast((sel3 - bias128)*rd + b4.w);
    __half2 q0h = __floats2half2_rn(v0, v1);
    __half2 q1h = __floats2half2_rn(v2, v3);
    float2 ov;
    *(__half2*)&ov.x = q0h; *(__half2*)&ov.y = q1h;
    *(float2*)(hl2h + (size_t)n*64 + c*8 + slot*2) = ov;
}

// ---------------- GEMM2: h2 = hl2 @ W2 -> fp16 + fused alpha2 ----------------
#define FMA4(acc, a, b) { acc.x += (a)*(b).x; acc.y += (a)*(b).y; acc.z += (a)*(b).z; acc.w += (a)*(b).w; }

__global__ __launch_bounds__(256) void k_gemm2(const __half2* __restrict__ hl2h, const float* __restrict__ W2,
                                               const float* __restrict__ asrc2, const float* __restrict__ adst2,
                                               __half2* __restrict__ h2h, float* __restrict__ as2, float* __restrict__ ad2,
                                               int N){
    __shared__ float sX[64*132];
    __shared__ float sW2[128*16];
    int tid = threadIdx.x;
    for (int i = tid; i < 128*16; i += 256) sW2[i] = W2[i];
    int row0 = blockIdx.x * 64;
    #pragma unroll
    for (int i = 0; i < 4; ++i){
        int q = i*256 + tid;
        int r = q >> 4, seg = q & 15;
        float4 raw = make_float4(0.f,0.f,0.f,0.f);
        if (row0 + r < N) raw = ((const float4*)(hl2h + (size_t)(row0+r)*64))[seg];
        const __half2* hp = (const __half2*)&raw;
        float* dst = &sX[r*132 + seg*8];
        #pragma unroll
        for (int j = 0; j < 4; ++j){
            float2 f = __half22float2(hp[j]);
            dst[2*j] = f.x; dst[2*j+1] = f.y;
        }
    }
    __syncthreads();
    int nd = tid >> 2;
    int cq = tid & 3, c0 = cq*4;
    int n = row0 + nd;
    float4 acc = make_float4(0.f,0.f,0.f,0.f);
    #pragma unroll 4
    for (int k4 = 0; k4 < 32; ++k4){
        float4 a  = *(const float4*)(&sX[nd*132 + k4*4]);
        float4 w0 = *(const float4*)(&sW2[(k4*4+0)*16 + c0]);
        float4 w1 = *(const float4*)(&sW2[(k4*4+1)*16 + c0]);
        float4 w2 = *(const float4*)(&sW2[(k4*4+2)*16 + c0]);
        float4 w3 = *(const float4*)(&sW2[(k4*4+3)*16 + c0]);
        FMA4(acc, a.x, w0); FMA4(acc, a.y, w1); FMA4(acc, a.z, w2); FMA4(acc, a.w, w3);
    }
    float ps = acc.x*asrc2[c0] + acc.y*asrc2[c0+1] + acc.z*asrc2[c0+2] + acc.w*asrc2[c0+3];
    float pd = acc.x*adst2[c0] + acc.y*adst2[c0+1] + acc.z*adst2[c0+2] + acc.w*adst2[c0+3];
    ps += __shfl_xor(ps, 1); ps += __shfl_xor(ps, 2);
    pd += __shfl_xor(pd, 1); pd += __shfl_xor(pd, 2);
    if (n < N){
        __half2 p0 = __floats2half2_rn(acc.x, acc.y);
        __half2 p1 = __floats2half2_rn(acc.z, acc.w);
        float2 ov;
        *(__half2*)&ov.x = p0; *(__half2*)&ov.y = p1;
        *(float2*)(h2h + (size_t)n*8 + cq*2) = ov;
        if (cq == 0){ as2[n] = ps; ad2[n] = pd; }
    }
}

// ---------------- layer-2 fused aggregation (half2 gather, 8 edges in flight) -> out ----------------
__global__ __launch_bounds__(256) void k_agg2(const __half2* __restrict__ h2h, const float* __restrict__ as2v,
                                              const float* __restrict__ ad2v,
                                              const int* __restrict__ offs, const int* __restrict__ esrc,
                                              const float* __restrict__ b2, float* __restrict__ out, int N){
    int n = blockIdx.x*4 + (threadIdx.x >> 6);
    if (n >= N) return;
    int l = threadIdx.x & 63;
    int e0 = offs[n], e1 = offs[n+1];
    float ad = ad2v[n];
    int eo = l >> 3, c2 = l & 7;
    float ax = 0.f, ay = 0.f, den = 0.f;
    for (int e = e0 + eo; e < e1; e += 8){
        int s = esrc[e];
        float w = __expf(lrelu(as2v[s] + ad));
        den += w;
        float2 f = __half22float2(h2h[(size_t)s*8 + c2]);
        ax += w * f.x; ay += w * f.y;
    }
    ax += __shfl_xor(ax, 8);  ay += __shfl_xor(ay, 8);  den += __shfl_xor(den, 8);
    ax += __shfl_xor(ax, 16); ay += __shfl_xor(ay, 16); den += __shfl_xor(den, 16);
    ax += __shfl_xor(ax, 32); ay += __shfl_xor(ay, 32); den += __shfl_xor(den, 32);
    if (eo == 0){
        float rd = 1.f / (den + 1e-16f);
        float2 bb = *(const float2*)(b2 + c2*2);
        float2 o = make_float2(ax*rd + bb.x, ay*rd + bb.y);
        *(float2*)(out + (size_t)n*16 + c2*2) = o;
    }
}

extern "C" void kernel_launch(void* const* d_in, const int* in_sizes, int n_in,
                              void* d_out, int out_size, void* d_ws, size_t ws_size,
                              hipStream_t stream){
    const float* x     = (const float*)d_in[0];
    const int*   ei    = (const int*)  d_in[1];
    const float* W1    = (const float*)d_in[2];
    const float* asrc1 = (const float*)d_in[3];
    const float* adst1 = (const float*)d_in[4];
    const float* b1    = (const float*)d_in[5];
    const float* W2    = (const float*)d_in[6];
    const float* asrc2 = (const float*)d_in[7];
    const float* adst2 = (const float*)d_in[8];
    const float* b2    = (const float*)d_in[9];
    float* out = (float*)d_out;

    const int N = in_sizes[0] / IN_CH;   // 100000
    const int E = in_sizes[1] / 2;       // 1600000
    const int ETOT = E + N;
    const int NBUCK = (N + NPB - 1) / NPB;   // 391

    char* p = (char*)d_ws;
    auto alloc = [&](size_t bytes) -> char* {
        char* r = p; p += (bytes + 255) & ~(size_t)255; return r;
    };
    __half2* h1h  = (__half2*)alloc((size_t)N * 64 * 4);
    __half2* hl2h = (__half2*)alloc((size_t)N * 64 * 4);
    unsigned char* h1q = (unsigned char*)alloc((size_t)N * 128);
    float2* asw  = (float2*)alloc((size_t)N * 8 * 8);
    float* ad1   = (float*)alloc((size_t)N * 8 * 4);
    __half2* h2h = (__half2*)alloc((size_t)N * 8 * 4);
    float* as2   = (float*)alloc((size_t)N * 4);
    float* ad2   = (float*)alloc((size_t)N * 4);
    int*   bcnt  = (int*)  alloc((size_t)MAXBUCK * 4);
    int*   boffs = (int*)  alloc((size_t)(MAXBUCK + 1) * 4);
    int*   bcur  = (int*)  alloc((size_t)MAXBUCK * 4);
    int*   offs  = (int*)  alloc((size_t)(N + 1) * 4);
    int*   esrc  = (int*)  alloc((size_t)ETOT * 4);
    int2*  ebuck = (int2*)hl2h;   // aliases hl2h; k_csr done before k_agg1 writes it

    (void)hipMemsetAsync(bcnt, 0, (size_t)NBUCK * 4, stream);

    const int GPART = 512;
    const int epb = (E + GPART - 1) / GPART;

    k_bhist   <<<GPART, 256, 0, stream>>>(ei + E, E, NBUCK, epb, bcnt);
    k_bscan   <<<1,     512, 0, stream>>>(bcnt, NBUCK, E, boffs, bcur);
    k_bscatter<<<GPART, 256, 0, stream>>>(ei, E, NBUCK, epb, bcur, ebuck);
    k_csr     <<<NBUCK, 256, 0, stream>>>(ebuck, boffs, N, E, offs, esrc);

    const int NT = (N + 63) / 64;           // 1563 row tiles
    const int G1 = NT < 512 ? NT : 512;     // 2 blocks/CU, persistent W1
    k_gemm1  <<<G1, 256, 0, stream>>>(x, W1, (__half*)h1h, N, NT);
    k_alpha1 <<<(N * HEADS + 255) / 256, 256, 0, stream>>>(h1h, asrc1, adst1, asw, ad1, h1q, N);

    // split k_agg1 into two node-range halves (profile visibility + scheduling)
    const int NH = ((N / 2) + 7) & ~7;   // 50000 -> multiple of 8
    k_agg1 <<<(NH + 7) / 8, 256, 0, stream>>>(h1q, asw, ad1, offs, esrc, b1, hl2h, 0, NH);
    k_agg1 <<<((N - NH) + 7) / 8, 256, 0, stream>>>(h1q, asw, ad1, offs, esrc, b1, hl2h, NH, N);

    k_gemm2  <<<(N + 63) / 64, 256, 0, stream>>>(hl2h, W2, asrc2, adst2, h2h, as2, ad2, N);
    k_agg2   <<<(N + 3) / 4, 256, 0, stream>>>(h2h, as2, ad2, offs, esrc, b2, out, N);
}